// Round 9
// baseline (209.677 us; speedup 1.0000x reference)
//
#include <hip/hip_runtime.h>
#include <hip/hip_bf16.h>

#define K_CLS 20
#define HIN 480
#define WIN 640
#define NPIX (HIN * WIN)
#define C_ 512
#define H_ 30
#define W_ 40
#define HW_ (H_ * W_)
#define NB_ 5
#define CNT_THRESH 10000
// out layout (fp32): pool_x[2048], NB, N, x_cropped[6*4*512*30*40]
#define XCROP_ELEMS (6 * 4 * C_ * H_ * W_)
#define ELEMS_PER_SN (C_ * H_ * W_)            // 614400 = one (s,n) slice
#define OUT_TOTAL (2050 + XCROP_ELEMS)

#define NBLK_STATS 300                 // NPIX/4/256 exactly

// native clang vector types: __builtin_nontemporal_store rejects
// HIP_vector_type (R5 compile fail) but accepts ext_vector_type.
typedef float f32x2 __attribute__((ext_vector_type(2)));
typedef float f32x4 __attribute__((ext_vector_type(4)));

// R9: 2 dispatches. R8 proved fusion is right (non-kernel residue ~4us vs
// ~45us for the plan_k dispatch) but the redundant in-block plan read ws
// at stride 400B -> 64 lines per wave-load -> fuse_k 72us. Fix: TRANSPOSED
// stats layout ws[c*300+blk] (column-major, 1200B contiguous per column);
// each wave reduces columns round-robin with lane-striped coalesced loads
// + 6-step shfl_xor tree. Aggregate plan traffic 512x120KB = 61MB
// coalesced L2 ~ 2us. part[][] LDS gone (was 315K bank conflicts).
#define F_CPB 4                        // channels per block
#define F_CGRP (C_ / F_CPB)            // 128
#define F_TPB 512
#define F_BLOCKS (4 * F_CGRP)          // 512

// ws int layout (column-major): ws[c * 300 + blk], c in 0..99
// c/20: 0=cnt(sum) 1=mnx(min) 2=mny(min) 3=mxx(max) 4=mxy(max)

__global__ void stats_k(const float* __restrict__ seg, int* __restrict__ ws) {
    __shared__ int s_cnt[K_CLS], s_mnx[K_CLS], s_mny[K_CLS], s_mxx[K_CLS], s_mxy[K_CLS];
    int t = threadIdx.x;
    if (t < K_CLS) { s_cnt[t] = 0; s_mnx[t] = WIN; s_mny[t] = HIN; s_mxx[t] = -1; s_mxy[t] = -1; }
    __syncthreads();

    int p = blockIdx.x * blockDim.x + t;                 // quad-pixel index, 0..76799
    const float4* base = (const float4*)(seg + (size_t)3 * K_CLS * NPIX) + p;
    float4 v = base[0];
    float b0 = v.x, b1 = v.y, b2 = v.z, b3 = v.w;
    int k0 = 0, k1 = 0, k2 = 0, k3 = 0;
    #pragma unroll
    for (int k = 1; k < K_CLS; k++) {                    // strict > : np.argmax tie-break
        float4 u = base[(size_t)k * (NPIX / 4)];
        if (u.x > b0) { b0 = u.x; k0 = k; }
        if (u.y > b1) { b1 = u.y; k1 = k; }
        if (u.z > b2) { b2 = u.z; k2 = k; }
        if (u.w > b3) { b3 = u.w; k3 = k; }
    }
    int x = (p * 4) % WIN, y = (p * 4) / WIN;            // quad never wraps a row (640%4==0)
    if (k0 == k1 && k1 == k2 && k2 == k3) {              // common case: uniform class
        atomicAdd(&s_cnt[k0], 4);
        atomicMin(&s_mnx[k0], x);     atomicMax(&s_mxx[k0], x + 3);
        atomicMin(&s_mny[k0], y);     atomicMax(&s_mxy[k0], y);
    } else {
        int ks[4] = {k0, k1, k2, k3};
        #pragma unroll
        for (int i = 0; i < 4; i++) {
            atomicAdd(&s_cnt[ks[i]], 1);
            atomicMin(&s_mnx[ks[i]], x + i);  atomicMax(&s_mxx[ks[i]], x + i);
            atomicMin(&s_mny[ks[i]], y);      atomicMax(&s_mxy[ks[i]], y);
        }
    }
    __syncthreads();
    if (t < 100) {                                       // per-block partial, TRANSPOSED
        int a = t / 20, c = t % 20;
        int val = (a == 0) ? s_cnt[c] : (a == 1) ? s_mnx[c] : (a == 2) ? s_mny[c]
                : (a == 3) ? s_mxx[c] : s_mxy[c];
        ws[t * NBLK_STATS + blockIdx.x] = val;           // column-major
    }
}

__global__ __launch_bounds__(F_TPB) void fuse_k(const float* __restrict__ feat,
                      const int* __restrict__ ws,
                      const float* __restrict__ pool_x,
                      float* __restrict__ out) {
    __shared__ float sf[F_CPB * HW_];                    // 19.2 KB feat slice
    __shared__ int st[100];
    __shared__ int s_nb[NB_ * 4];                        // final boxes

    int t  = threadIdx.x;
    int n  = blockIdx.x / F_CGRP;                        // batch, 0..3
    int c0 = (blockIdx.x % F_CGRP) * F_CPB;              // channel group base

    // ---- phase A: stage (n, c0..c0+3) slice into LDS; fuse s=5 identity
    // copy (out slice 20+n has the same linear layout as feat).
    const float* src = feat + ((size_t)n * C_ + c0) * HW_;
    float* cdst = out + 2050 + (size_t)(20 + n) * ELEMS_PER_SN + (size_t)c0 * HW_;
    for (int i = t; i < (F_CPB * HW_) / 4; i += F_TPB) {
        f32x4 v = ((const f32x4*)src)[i];
        ((f32x4*)sf)[i] = v;
        // dest only 8B-aligned (2050%4==2) -> two f32x2 NT stores
        f32x2 lo = {v.x, v.y}, hi = {v.z, v.w};
        __builtin_nontemporal_store(lo, (f32x2*)(cdst + i * 4));
        __builtin_nontemporal_store(hi, (f32x2*)(cdst + i * 4 + 2));
    }
    if (blockIdx.x == 0) {                               // header: pool_x, NB, N
        for (int i = t; i < 1024; i += F_TPB)
            ((float2*)out)[i] = ((const float2*)pool_x)[i];
        if (t == 0) { out[2048] = 5.0f; out[2049] = 4.0f; }
    }

    // ---- phase P: redundant per-block plan, coalesced + wave-reduced.
    // Each wave owns columns (wave, wave+8, ...); lanes stripe the 300
    // contiguous partials of a column (5 coalesced wave-loads), then a
    // 6-step shfl_xor tree combines across the 64 lanes.
    {
        int wave = t >> 6, lane = t & 63;
        for (int c = wave; c < 100; c += 8) {
            int a = c / 20;
            int acc = (a == 0) ? 0 : (a == 1) ? WIN : (a == 2) ? HIN : -1;
            for (int i = lane; i < NBLK_STATS; i += 64) {
                int v = ws[c * NBLK_STATS + i];
                if (a == 0)      acc += v;
                else if (a <= 2) acc = min(acc, v);
                else             acc = max(acc, v);
            }
            #pragma unroll
            for (int off = 32; off > 0; off >>= 1) {
                int o = __shfl_xor(acc, off, 64);
                if (a == 0)      acc += o;
                else if (a <= 2) acc = min(acc, o);
                else             acc = max(acc, o);
            }
            if (lane == 0) st[c] = acc;
        }
    }
    __syncthreads();
    if (t == 0) {
        int* cnt = st;
        int* mnx = st + 20; int* mny = st + 40; int* mxx = st + 60; int* mxy = st + 80;

        // np.unique -> sorted present ids; drop smallest present id
        int firstp = -1;
        for (int i = 0; i < K_CLS; i++) if (cnt[i] > 0) { firstp = i; break; }
        int order[K_CLS]; int nc = 0;
        for (int i = 0; i < K_CLS; i++)
            if (cnt[i] > 0 && i != firstp) order[nc++] = i;

        // stable insertion sort, descending by count
        for (int i = 1; i < nc; i++) {
            int key = order[i]; int j = i - 1;
            while (j >= 0 && cnt[order[j]] < cnt[key]) { order[j + 1] = order[j]; j--; }
            order[j + 1] = key;
        }

        int nsel = 0;
        for (int i = 0; i < nc && nsel < NB_ - 2; i++) {
            int b = order[i];
            if (cnt[b] > CNT_THRESH) {
                s_nb[nsel * 4 + 0] = mnx[b] >> 4;
                s_nb[nsel * 4 + 1] = mny[b] >> 4;
                s_nb[nsel * 4 + 2] = mxx[b] >> 4;
                s_nb[nsel * 4 + 3] = mxy[b] >> 4;
                nsel++;
            }
        }
        const int bb[5][4] = {
            {W_ / 4, H_ / 4, 3 * W_ / 4, 3 * H_ / 4},
            {0, 0, W_ / 3, H_},
            {0, 0, W_, H_ / 3},
            {2 * W_ / 3, 0, W_, H_},
            {0, 2 * H_ / 3, W_, H_}
        };
        for (int i = 0; nsel < NB_; i++, nsel++) {
            s_nb[nsel * 4 + 0] = bb[i][0];
            s_nb[nsel * 4 + 1] = bb[i][1];
            s_nb[nsel * 4 + 2] = bb[i][2];
            s_nb[nsel * 4 + 3] = bb[i][3];
        }
    }
    __syncthreads();                                     // sf + s_nb ready

    // ---- phase E: emit 5 bilinear crop slices from the staged slice
    for (int b = 0; b < NB_; b++) {
        int x0 = s_nb[b * 4 + 0], y0 = s_nb[b * 4 + 1];
        int x1 = s_nb[b * 4 + 2], y1 = s_nb[b * 4 + 3];
        int iw = max(x1 - x0, 1), ih = max(y1 - y0, 1);
        int cb = y0 * W_ + x0;                           // crop base in channel slice
        float sx = (float)iw * (1.0f / (float)W_);
        float sy = (float)ih * (1.0f / (float)H_);
        float* ob = out + 2050 + (size_t)(5 * n + b) * ELEMS_PER_SN + (size_t)c0 * HW_;

        for (int hw = t; hw < HW_; hw += F_TPB) {
            int h = hw / W_;
            int w = hw - h * W_;

            // half-pixel-center bilinear; scale<=1 so antialias inert,
            // edge renorm == clamp. CLAMP ORDER (R1 bug): hi tap =
            // unclamped lo + 1, THEN clamp. fx,fy >= -0.5 -> lo_u >= -1.
            float fy  = ((float)h + 0.5f) * sy - 0.5f;
            float flY = floorf(fy);
            float ty  = fy - flY;
            int ylo_u = (int)flY;
            int ylo = max(ylo_u, 0);
            int yhi = min(ylo_u + 1, ih - 1);

            float fx  = ((float)w + 0.5f) * sx - 0.5f;
            float flX = floorf(fx);
            float tx  = fx - flX;
            int xlo_u = (int)flX;
            int xlo = max(xlo_u, 0);
            int xhi = min(xlo_u + 1, iw - 1);

            // indices within one channel slice; max (y1-1)*40+x1-1 <= 1199
            int i00 = cb + ylo * W_ + xlo, i01 = cb + ylo * W_ + xhi;
            int i10 = cb + yhi * W_ + xlo, i11 = cb + yhi * W_ + xhi;

            float* op = ob + hw;
            #pragma unroll
            for (int j = 0; j < F_CPB; j++) {            // taps shared by channels
                const float* sp = sf + j * HW_;          // j*4800B folds into ds imm
                float v00 = sp[i00], v01 = sp[i01];
                float v10 = sp[i10], v11 = sp[i11];
                float top = v00 + tx * (v01 - v00);      // 3-FMA lerp
                float bot = v10 + tx * (v11 - v10);
                __builtin_nontemporal_store(top + ty * (bot - top), op + j * HW_);
            }
        }
    }
}

extern "C" void kernel_launch(void* const* d_in, const int* in_sizes, int n_in,
                              void* d_out, int out_size, void* d_ws, size_t ws_size,
                              hipStream_t stream) {
    const float* seg    = (const float*)d_in[0];
    const float* feat   = (const float*)d_in[1];
    const float* pool_x = (const float*)d_in[2];
    float* out = (float*)d_out;
    int* ws = (int*)d_ws;

    stats_k<<<NBLK_STATS, 256, 0, stream>>>(seg, ws);
    fuse_k<<<F_BLOCKS, F_TPB, 0, stream>>>(feat, ws, pool_x, out);
}

// Round 10
// 183.247 us; speedup vs baseline: 1.1442x; 1.1442x over previous
//
#include <hip/hip_runtime.h>
#include <hip/hip_bf16.h>

#define K_CLS 20
#define HIN 480
#define WIN 640
#define NPIX (HIN * WIN)
#define C_ 512
#define H_ 30
#define W_ 40
#define HW_ (H_ * W_)
#define NB_ 5
#define CNT_THRESH 10000
// out layout (fp32): pool_x[2048], NB, N, x_cropped[6*4*512*30*40]
#define XCROP_ELEMS (6 * 4 * C_ * H_ * W_)
#define ELEMS_PER_SN (C_ * H_ * W_)            // 614400 = one (s,n) slice
#define OUT_TOTAL (2050 + XCROP_ELEMS)

#define NBLK_STATS 300                 // NPIX/4/256 exactly

// native clang vector types: __builtin_nontemporal_store rejects
// HIP_vector_type (R5 compile fail) but accepts ext_vector_type.
typedef float f32x2 __attribute__((ext_vector_type(2)));
typedef float f32x4 __attribute__((ext_vector_type(4)));

// R10: 2 dispatches; SERIAL PLANNER PARALLELIZED. The cross-round ledger
// pinned ~40us on the single-lane t==0 selection block (~400 serial loop
// iters of LDS loads+branches at 150-200cyc each) — present since R0 in
// plan_k (42us for a 1-block kernel!) and copied into fuse_k (R8 +46us,
// R9 +50us). R9's coalescing null + identical bank-conflict count (315K
// with part[][] deleted) falsified the read-pattern theory. Now: lane k
// owns class k; firstp = ballot+ffs; stable desc rank = 20-step compare
// loop; selpos = shfl-popcount of passing-lower-rank; bb pad unrolled.
// ~25 parallel steps, <1us. ws back to row-major (R9 transpose caused
// 16-way false sharing per 64B line in stats_k's scatter).
#define F_CPB 4                        // channels per block
#define F_CGRP (C_ / F_CPB)            // 128
#define F_TPB 512
#define F_BLOCKS (4 * F_CGRP)          // 512

// ws int layout: [block][cnt20|mnx20|mny20|mxx20|mxy20] * 300 (row-major)

__global__ void stats_k(const float* __restrict__ seg, int* __restrict__ ws) {
    __shared__ int s_cnt[K_CLS], s_mnx[K_CLS], s_mny[K_CLS], s_mxx[K_CLS], s_mxy[K_CLS];
    int t = threadIdx.x;
    if (t < K_CLS) { s_cnt[t] = 0; s_mnx[t] = WIN; s_mny[t] = HIN; s_mxx[t] = -1; s_mxy[t] = -1; }
    __syncthreads();

    int p = blockIdx.x * blockDim.x + t;                 // quad-pixel index, 0..76799
    const float4* base = (const float4*)(seg + (size_t)3 * K_CLS * NPIX) + p;
    float4 v = base[0];
    float b0 = v.x, b1 = v.y, b2 = v.z, b3 = v.w;
    int k0 = 0, k1 = 0, k2 = 0, k3 = 0;
    #pragma unroll
    for (int k = 1; k < K_CLS; k++) {                    // strict > : np.argmax tie-break
        float4 u = base[(size_t)k * (NPIX / 4)];
        if (u.x > b0) { b0 = u.x; k0 = k; }
        if (u.y > b1) { b1 = u.y; k1 = k; }
        if (u.z > b2) { b2 = u.z; k2 = k; }
        if (u.w > b3) { b3 = u.w; k3 = k; }
    }
    int x = (p * 4) % WIN, y = (p * 4) / WIN;            // quad never wraps a row (640%4==0)
    if (k0 == k1 && k1 == k2 && k2 == k3) {              // common case: uniform class
        atomicAdd(&s_cnt[k0], 4);
        atomicMin(&s_mnx[k0], x);     atomicMax(&s_mxx[k0], x + 3);
        atomicMin(&s_mny[k0], y);     atomicMax(&s_mxy[k0], y);
    } else {
        int ks[4] = {k0, k1, k2, k3};
        #pragma unroll
        for (int i = 0; i < 4; i++) {
            atomicAdd(&s_cnt[ks[i]], 1);
            atomicMin(&s_mnx[ks[i]], x + i);  atomicMax(&s_mxx[ks[i]], x + i);
            atomicMin(&s_mny[ks[i]], y);      atomicMax(&s_mxy[ks[i]], y);
        }
    }
    __syncthreads();
    if (t < 100) {                                       // per-block partial, row-major
        int a = t / 20, c = t % 20;
        int val = (a == 0) ? s_cnt[c] : (a == 1) ? s_mnx[c] : (a == 2) ? s_mny[c]
                : (a == 3) ? s_mxx[c] : s_mxy[c];
        ws[blockIdx.x * 100 + t] = val;
    }
}

__global__ __launch_bounds__(F_TPB) void fuse_k(const float* __restrict__ feat,
                      const int* __restrict__ ws,
                      const float* __restrict__ pool_x,
                      float* __restrict__ out) {
    __shared__ float sf[F_CPB * HW_];                    // 19.2 KB feat slice
    __shared__ int part[5][100];
    __shared__ int st[100];
    __shared__ int s_nb[NB_ * 4];                        // final boxes

    int t  = threadIdx.x;
    int n  = blockIdx.x / F_CGRP;                        // batch, 0..3
    int c0 = (blockIdx.x % F_CGRP) * F_CPB;              // channel group base

    // ---- phase A: stage (n, c0..c0+3) slice into LDS; fuse s=5 identity
    // copy (out slice 20+n has the same linear layout as feat).
    const float* src = feat + ((size_t)n * C_ + c0) * HW_;
    float* cdst = out + 2050 + (size_t)(20 + n) * ELEMS_PER_SN + (size_t)c0 * HW_;
    for (int i = t; i < (F_CPB * HW_) / 4; i += F_TPB) {
        f32x4 v = ((const f32x4*)src)[i];
        ((f32x4*)sf)[i] = v;
        // dest only 8B-aligned (2050%4==2) -> two f32x2 NT stores
        f32x2 lo = {v.x, v.y}, hi = {v.z, v.w};
        __builtin_nontemporal_store(lo, (f32x2*)(cdst + i * 4));
        __builtin_nontemporal_store(hi, (f32x2*)(cdst + i * 4 + 2));
    }
    if (blockIdx.x == 0) {                               // header: pool_x, NB, N
        for (int i = t; i < 1024; i += F_TPB)
            ((float2*)out)[i] = ((const float2*)pool_x)[i];
        if (t == 0) { out[2048] = 5.0f; out[2049] = 4.0f; }
    }

    // ---- phase P1: reduce 300 partial records (R8's measured-cheap form)
    if (t < 500) {
        int c = t % 100, chunk = t / 100;                // 5 chunks x 60 records
        int a = c / 20;
        int acc = (a == 0) ? 0 : (a == 1) ? WIN : (a == 2) ? HIN : -1;
        #pragma unroll
        for (int i = 0; i < 60; i++) {
            int v = ws[(chunk * 60 + i) * 100 + c];
            if (a == 0)      acc += v;
            else if (a <= 2) acc = min(acc, v);
            else             acc = max(acc, v);
        }
        part[chunk][c] = acc;
    }
    __syncthreads();
    if (t < 100) {
        int a = t / 20;
        int acc = part[0][t];
        #pragma unroll
        for (int i = 1; i < 5; i++) {
            int v = part[i][t];
            if (a == 0)      acc += v;
            else if (a <= 2) acc = min(acc, v);
            else             acc = max(acc, v);
        }
        st[t] = acc;
    }
    __syncthreads();

    // ---- phase P2: WAVE-PARALLEL planner (wave 0 only).
    // Semantics identical to the serial version (test-passing since R0):
    // drop smallest present id; stable desc-by-count rank (ties: lower id
    // first, == insertion sort); select first <=3 passing CNT_THRESH in
    // rank order; pad with bb[] rows.
    if (t < 64) {
        int k = t;
        bool valid = k < K_CLS;
        int ck = valid ? st[k] : 0;
        bool present = valid && ck > 0;
        unsigned long long pmask = __ballot(present);
        int firstp = __ffsll((long long)pmask) - 1;      // >=0 (307200 px present)
        bool cand = present && (k != firstp);
        bool pass = cand && ck > CNT_THRESH;

        int rank = 0;                                    // among candidates
        #pragma unroll
        for (int j = 0; j < K_CLS; j++) {
            int cj = st[j];
            bool candj = (cj > 0) && (j != firstp);
            if (candj && (cj > ck || (cj == ck && j < k))) rank++;
        }
        int selpos = 0;                                  // passing with lower rank
        #pragma unroll
        for (int j = 0; j < K_CLS; j++) {
            int rj = __shfl(rank, j, 64);
            int pj = __shfl((int)pass, j, 64);
            if (pj && rj < rank) selpos++;
        }
        bool selected = pass && selpos < (NB_ - 2);
        if (selected) {
            s_nb[selpos * 4 + 0] = st[20 + k] >> 4;      // mnx
            s_nb[selpos * 4 + 1] = st[40 + k] >> 4;      // mny
            s_nb[selpos * 4 + 2] = st[60 + k] >> 4;      // mxx
            s_nb[selpos * 4 + 3] = st[80 + k] >> 4;      // mxy
        }
        int nsel = __popcll(__ballot(selected));         // <= 3
        // pad slots nsel..4 with bb[0..]; lane `nsel+i` writes bb[i]
        #define BBW(i, A, B, Cc, D) \
            if (t == nsel + i && t < NB_) { \
                s_nb[t * 4 + 0] = A; s_nb[t * 4 + 1] = B; \
                s_nb[t * 4 + 2] = Cc; s_nb[t * 4 + 3] = D; }
        BBW(0, W_ / 4, H_ / 4, 3 * W_ / 4, 3 * H_ / 4)
        BBW(1, 0, 0, W_ / 3, H_)
        BBW(2, 0, 0, W_, H_ / 3)
        BBW(3, 2 * W_ / 3, 0, W_, H_)
        BBW(4, 0, 2 * H_ / 3, W_, H_)
        #undef BBW
    }
    __syncthreads();                                     // sf + s_nb ready

    // ---- phase E: emit 5 bilinear crop slices from the staged slice
    for (int b = 0; b < NB_; b++) {
        int x0 = s_nb[b * 4 + 0], y0 = s_nb[b * 4 + 1];
        int x1 = s_nb[b * 4 + 2], y1 = s_nb[b * 4 + 3];
        int iw = max(x1 - x0, 1), ih = max(y1 - y0, 1);
        int cb = y0 * W_ + x0;                           // crop base in channel slice
        float sx = (float)iw * (1.0f / (float)W_);
        float sy = (float)ih * (1.0f / (float)H_);
        float* ob = out + 2050 + (size_t)(5 * n + b) * ELEMS_PER_SN + (size_t)c0 * HW_;

        for (int hw = t; hw < HW_; hw += F_TPB) {
            int h = hw / W_;
            int w = hw - h * W_;

            // half-pixel-center bilinear; scale<=1 so antialias inert,
            // edge renorm == clamp. CLAMP ORDER (R1 bug): hi tap =
            // unclamped lo + 1, THEN clamp. fx,fy >= -0.5 -> lo_u >= -1.
            float fy  = ((float)h + 0.5f) * sy - 0.5f;
            float flY = floorf(fy);
            float ty  = fy - flY;
            int ylo_u = (int)flY;
            int ylo = max(ylo_u, 0);
            int yhi = min(ylo_u + 1, ih - 1);

            float fx  = ((float)w + 0.5f) * sx - 0.5f;
            float flX = floorf(fx);
            float tx  = fx - flX;
            int xlo_u = (int)flX;
            int xlo = max(xlo_u, 0);
            int xhi = min(xlo_u + 1, iw - 1);

            // indices within one channel slice; max (y1-1)*40+x1-1 <= 1199
            int i00 = cb + ylo * W_ + xlo, i01 = cb + ylo * W_ + xhi;
            int i10 = cb + yhi * W_ + xlo, i11 = cb + yhi * W_ + xhi;

            float* op = ob + hw;
            #pragma unroll
            for (int j = 0; j < F_CPB; j++) {            // taps shared by channels
                const float* sp = sf + j * HW_;          // j*4800B folds into ds imm
                float v00 = sp[i00], v01 = sp[i01];
                float v10 = sp[i10], v11 = sp[i11];
                float top = v00 + tx * (v01 - v00);      // 3-FMA lerp
                float bot = v10 + tx * (v11 - v10);
                __builtin_nontemporal_store(top + ty * (bot - top), op + j * HW_);
            }
        }
    }
}

extern "C" void kernel_launch(void* const* d_in, const int* in_sizes, int n_in,
                              void* d_out, int out_size, void* d_ws, size_t ws_size,
                              hipStream_t stream) {
    const float* seg    = (const float*)d_in[0];
    const float* feat   = (const float*)d_in[1];
    const float* pool_x = (const float*)d_in[2];
    float* out = (float*)d_out;
    int* ws = (int*)d_ws;

    stats_k<<<NBLK_STATS, 256, 0, stream>>>(seg, ws);
    fuse_k<<<F_BLOCKS, F_TPB, 0, stream>>>(feat, ws, pool_x, out);
}

// Round 11
// 180.299 us; speedup vs baseline: 1.1629x; 1.0164x over previous
//
#include <hip/hip_runtime.h>
#include <hip/hip_bf16.h>

#define K_CLS 20
#define HIN 480
#define WIN 640
#define NPIX (HIN * WIN)
#define C_ 512
#define H_ 30
#define W_ 40
#define HW_ (H_ * W_)
#define NB_ 5
#define CNT_THRESH 10000
// out layout (fp32): pool_x[2048], NB, N, x_cropped[6*4*512*30*40]
#define XCROP_ELEMS (6 * 4 * C_ * H_ * W_)
#define ELEMS_PER_SN (C_ * H_ * W_)            // 614400 = one (s,n) slice
#define OUT_TOTAL (2050 + XCROP_ELEMS)

#define NBLK_STATS 300                 // NPIX/4/256 exactly
#define NODE_OFF (NBLK_STATS * 100)    // ws int offset of the 5 node boxes

// native clang vector types: __builtin_nontemporal_store rejects
// HIP_vector_type (R5 compile fail) but accepts ext_vector_type.
typedef float f32x2 __attribute__((ext_vector_type(2)));
typedef float f32x4 __attribute__((ext_vector_type(4)));

// R11: 3 dispatches, all parallel-only. Ledger after R10: fuse ~54us =
// A(~4) + E(~26) + ~20us of redundant P1 — 512 blocks re-reading the SAME
// 120KB of ws (1875 lines x 512 readers = L2/L3 hot-line serialization;
// explains R9's coalescing null). Fix: de-duplicate. plan_k returns as a
// 1-block kernel but with ZERO serial work (R0's chunked reduce + R10's
// wave-parallel planner + header copy) -> ~5us incl. launch, vs 42us for
// its serial ancestor. fuse_k = stage + 20-int box load + 1 barrier + emit.
#define F_CPB 4                        // channels per block
#define F_CGRP (C_ / F_CPB)            // 128
#define F_TPB 512
#define F_BLOCKS (4 * F_CGRP)          // 512

// ws int layout: [block][cnt20|mnx20|mny20|mxx20|mxy20] * 300, boxes at NODE_OFF

__global__ void stats_k(const float* __restrict__ seg, int* __restrict__ ws) {
    __shared__ int s_cnt[K_CLS], s_mnx[K_CLS], s_mny[K_CLS], s_mxx[K_CLS], s_mxy[K_CLS];
    int t = threadIdx.x;
    if (t < K_CLS) { s_cnt[t] = 0; s_mnx[t] = WIN; s_mny[t] = HIN; s_mxx[t] = -1; s_mxy[t] = -1; }
    __syncthreads();

    int p = blockIdx.x * blockDim.x + t;                 // quad-pixel index, 0..76799
    const float4* base = (const float4*)(seg + (size_t)3 * K_CLS * NPIX) + p;
    float4 v = base[0];
    float b0 = v.x, b1 = v.y, b2 = v.z, b3 = v.w;
    int k0 = 0, k1 = 0, k2 = 0, k3 = 0;
    #pragma unroll
    for (int k = 1; k < K_CLS; k++) {                    // strict > : np.argmax tie-break
        float4 u = base[(size_t)k * (NPIX / 4)];
        if (u.x > b0) { b0 = u.x; k0 = k; }
        if (u.y > b1) { b1 = u.y; k1 = k; }
        if (u.z > b2) { b2 = u.z; k2 = k; }
        if (u.w > b3) { b3 = u.w; k3 = k; }
    }
    int x = (p * 4) % WIN, y = (p * 4) / WIN;            // quad never wraps a row (640%4==0)
    if (k0 == k1 && k1 == k2 && k2 == k3) {              // common case: uniform class
        atomicAdd(&s_cnt[k0], 4);
        atomicMin(&s_mnx[k0], x);     atomicMax(&s_mxx[k0], x + 3);
        atomicMin(&s_mny[k0], y);     atomicMax(&s_mxy[k0], y);
    } else {
        int ks[4] = {k0, k1, k2, k3};
        #pragma unroll
        for (int i = 0; i < 4; i++) {
            atomicAdd(&s_cnt[ks[i]], 1);
            atomicMin(&s_mnx[ks[i]], x + i);  atomicMax(&s_mxx[ks[i]], x + i);
            atomicMin(&s_mny[ks[i]], y);      atomicMax(&s_mxy[ks[i]], y);
        }
    }
    __syncthreads();
    if (t < 100) {                                       // per-block partial, row-major
        int a = t / 20, c = t % 20;
        int val = (a == 0) ? s_cnt[c] : (a == 1) ? s_mnx[c] : (a == 2) ? s_mny[c]
                : (a == 3) ? s_mxx[c] : s_mxy[c];
        ws[blockIdx.x * 100 + t] = val;
    }
}

// 1-block plan: chunked reduce (R0-proven) + wave-parallel select
// (R10-proven) + header copy. No serial section anywhere.
__global__ void plan_k(int* __restrict__ ws, const float* __restrict__ pool_x,
                       float* __restrict__ out) {
    __shared__ int part[10][100];
    __shared__ int st[100];
    int t = threadIdx.x;                 // 0..1023

    // header: 2048 floats of pool_x as 1024 float2, then {NB, N}
    ((float2*)out)[t] = ((const float2*)pool_x)[t];
    if (t == 0) { out[2048] = 5.0f; out[2049] = 4.0f; }

    if (t < 1000) {
        int c = t % 100, chunk = t / 100;
        int a = c / 20;
        int acc = (a == 0) ? 0 : (a == 1) ? WIN : (a == 2) ? HIN : -1;
        #pragma unroll
        for (int i = 0; i < 30; i++) {
            int v = ws[(chunk * 30 + i) * 100 + c];
            if (a == 0)      acc += v;
            else if (a <= 2) acc = min(acc, v);
            else             acc = max(acc, v);
        }
        part[chunk][c] = acc;
    }
    __syncthreads();
    if (t < 100) {
        int a = t / 20;
        int acc = part[0][t];
        #pragma unroll
        for (int i = 1; i < 10; i++) {
            int v = part[i][t];
            if (a == 0)      acc += v;
            else if (a <= 2) acc = min(acc, v);
            else             acc = max(acc, v);
        }
        st[t] = acc;
    }
    __syncthreads();

    // wave-parallel planner (wave 0). Semantics == serial original:
    // drop smallest present id; stable desc-by-count rank (ties: lower
    // id first); first <=3 passing CNT_THRESH in rank order; bb pad.
    if (t < 64) {
        int k = t;
        bool valid = k < K_CLS;
        int ck = valid ? st[k] : 0;
        bool present = valid && ck > 0;
        unsigned long long pmask = __ballot(present);
        int firstp = __ffsll((long long)pmask) - 1;      // >=0 (307200 px present)
        bool pass = present && (k != firstp) && ck > CNT_THRESH;

        int rank = 0;                                    // among candidates
        #pragma unroll
        for (int j = 0; j < K_CLS; j++) {
            int cj = st[j];
            bool candj = (cj > 0) && (j != firstp);
            if (candj && (cj > ck || (cj == ck && j < k))) rank++;
        }
        int selpos = 0;                                  // passing with lower rank
        #pragma unroll
        for (int j = 0; j < K_CLS; j++) {
            int rj = __shfl(rank, j, 64);
            int pj = __shfl((int)pass, j, 64);
            if (pj && rj < rank) selpos++;
        }
        bool selected = pass && selpos < (NB_ - 2);
        int* nb = ws + NODE_OFF;
        if (selected) {
            nb[selpos * 4 + 0] = st[20 + k] >> 4;        // mnx
            nb[selpos * 4 + 1] = st[40 + k] >> 4;        // mny
            nb[selpos * 4 + 2] = st[60 + k] >> 4;        // mxx
            nb[selpos * 4 + 3] = st[80 + k] >> 4;        // mxy
        }
        int nsel = __popcll(__ballot(selected));         // <= 3
        #define BBW(i, A, B, Cc, D) \
            if (t == nsel + i && t < NB_) { \
                nb[t * 4 + 0] = A; nb[t * 4 + 1] = B; \
                nb[t * 4 + 2] = Cc; nb[t * 4 + 3] = D; }
        BBW(0, W_ / 4, H_ / 4, 3 * W_ / 4, 3 * H_ / 4)
        BBW(1, 0, 0, W_ / 3, H_)
        BBW(2, 0, 0, W_, H_ / 3)
        BBW(3, 2 * W_ / 3, 0, W_, H_)
        BBW(4, 0, 2 * H_ / 3, W_, H_)
        #undef BBW
    }
}

__global__ __launch_bounds__(F_TPB) void fuse_k(const float* __restrict__ feat,
                      const int* __restrict__ nb,
                      float* __restrict__ out) {
    __shared__ float sf[F_CPB * HW_];                    // 19.2 KB feat slice
    __shared__ int s_nb[NB_ * 4];                        // final boxes

    int t  = threadIdx.x;
    int n  = blockIdx.x / F_CGRP;                        // batch, 0..3
    int c0 = (blockIdx.x % F_CGRP) * F_CPB;              // channel group base

    if (t < NB_ * 4) s_nb[t] = nb[t];                    // 20-int box load

    // ---- stage (n, c0..c0+3) slice into LDS; fuse s=5 identity copy
    // (out slice 20+n has the same linear layout as feat).
    const float* src = feat + ((size_t)n * C_ + c0) * HW_;
    float* cdst = out + 2050 + (size_t)(20 + n) * ELEMS_PER_SN + (size_t)c0 * HW_;
    for (int i = t; i < (F_CPB * HW_) / 4; i += F_TPB) {
        f32x4 v = ((const f32x4*)src)[i];
        ((f32x4*)sf)[i] = v;
        // dest only 8B-aligned (2050%4==2) -> two f32x2 NT stores
        f32x2 lo = {v.x, v.y}, hi = {v.z, v.w};
        __builtin_nontemporal_store(lo, (f32x2*)(cdst + i * 4));
        __builtin_nontemporal_store(hi, (f32x2*)(cdst + i * 4 + 2));
    }
    __syncthreads();                                     // sf + s_nb ready

    // ---- emit 5 bilinear crop slices from the staged slice
    for (int b = 0; b < NB_; b++) {
        int x0 = s_nb[b * 4 + 0], y0 = s_nb[b * 4 + 1];
        int x1 = s_nb[b * 4 + 2], y1 = s_nb[b * 4 + 3];
        int iw = max(x1 - x0, 1), ih = max(y1 - y0, 1);
        int cb = y0 * W_ + x0;                           // crop base in channel slice
        float sx = (float)iw * (1.0f / (float)W_);
        float sy = (float)ih * (1.0f / (float)H_);
        float* ob = out + 2050 + (size_t)(5 * n + b) * ELEMS_PER_SN + (size_t)c0 * HW_;

        for (int hw = t; hw < HW_; hw += F_TPB) {
            int h = hw / W_;
            int w = hw - h * W_;

            // half-pixel-center bilinear; scale<=1 so antialias inert,
            // edge renorm == clamp. CLAMP ORDER (R1 bug): hi tap =
            // unclamped lo + 1, THEN clamp. fx,fy >= -0.5 -> lo_u >= -1.
            float fy  = ((float)h + 0.5f) * sy - 0.5f;
            float flY = floorf(fy);
            float ty  = fy - flY;
            int ylo_u = (int)flY;
            int ylo = max(ylo_u, 0);
            int yhi = min(ylo_u + 1, ih - 1);

            float fx  = ((float)w + 0.5f) * sx - 0.5f;
            float flX = floorf(fx);
            float tx  = fx - flX;
            int xlo_u = (int)flX;
            int xlo = max(xlo_u, 0);
            int xhi = min(xlo_u + 1, iw - 1);

            // indices within one channel slice; max (y1-1)*40+x1-1 <= 1199
            int i00 = cb + ylo * W_ + xlo, i01 = cb + ylo * W_ + xhi;
            int i10 = cb + yhi * W_ + xlo, i11 = cb + yhi * W_ + xhi;

            float* op = ob + hw;
            #pragma unroll
            for (int j = 0; j < F_CPB; j++) {            // taps shared by channels
                const float* sp = sf + j * HW_;          // j*4800B folds into ds imm
                float v00 = sp[i00], v01 = sp[i01];
                float v10 = sp[i10], v11 = sp[i11];
                float top = v00 + tx * (v01 - v00);      // 3-FMA lerp
                float bot = v10 + tx * (v11 - v10);
                __builtin_nontemporal_store(top + ty * (bot - top), op + j * HW_);
            }
        }
    }
}

extern "C" void kernel_launch(void* const* d_in, const int* in_sizes, int n_in,
                              void* d_out, int out_size, void* d_ws, size_t ws_size,
                              hipStream_t stream) {
    const float* seg    = (const float*)d_in[0];
    const float* feat   = (const float*)d_in[1];
    const float* pool_x = (const float*)d_in[2];
    float* out = (float*)d_out;
    int* ws = (int*)d_ws;

    stats_k<<<NBLK_STATS, 256, 0, stream>>>(seg, ws);
    plan_k<<<1, 1024, 0, stream>>>(ws, pool_x, out);
    fuse_k<<<F_BLOCKS, F_TPB, 0, stream>>>(feat, ws + NODE_OFF, out);
}